// Round 9
// baseline (181.793 us; speedup 1.0000x reference)
//
#include <hip/hip_runtime.h>

#define HH 128
#define WW 128
#define CC 64
#define IMG (HH*WW*CC)

// tile: 8 rows x 4 cols = 32 px/block, 1 px per thread (8 lanes x 8 ch)
// halo: 12 rows x 8 cols = 96 positions
// LDS:  [pos(96)][mat(2)][slot(8)] uint4 (each = 8 bf16 channels) = 24576 B

__device__ __forceinline__ unsigned pack2bf(float a, float b){
  unsigned ua = __float_as_uint(a), ub = __float_as_uint(b);
  ua = (ua + 0x7fffu + ((ua>>16)&1u)) >> 16;            // RTN
  ub = (ub + 0x7fffu + ((ub>>16)&1u)) >> 16;
  return ua | (ub<<16);
}

__device__ __forceinline__ void unpack8(uint4 u, float* f){
  f[0]=__uint_as_float(u.x<<16); f[1]=__uint_as_float(u.x&0xffff0000u);
  f[2]=__uint_as_float(u.y<<16); f[3]=__uint_as_float(u.y&0xffff0000u);
  f[4]=__uint_as_float(u.z<<16); f[5]=__uint_as_float(u.z&0xffff0000u);
  f[6]=__uint_as_float(u.w<<16); f[7]=__uint_as_float(u.w&0xffff0000u);
}

template<int CTRL>
__device__ __forceinline__ float dpp_addstep(float x){
  int p = __builtin_amdgcn_update_dpp(0, __float_as_int(x), CTRL, 0xf, 0xf, true);
  return x + __int_as_float(p);
}
// sum across 8 consecutive lanes (groups aligned to lane&~7) — pure VALU/DPP
__device__ __forceinline__ float reduce8(float x){
  x = dpp_addstep<0xB1>(x);    // xor 1
  x = dpp_addstep<0x4E>(x);    // xor 2
  x = dpp_addstep<0x141>(x);   // row_half_mirror
  return x;
}

__global__ __launch_bounds__(256, 6) void local_attn_kernel(
    const float* __restrict__ main_,
    const float* __restrict__ main_value,
    const float* __restrict__ ref,
    const float* __restrict__ ref_value,
    float* __restrict__ out)
{
    __shared__ uint4 kv4[96*2*8];   // 24576 B -> 6 blocks/CU

    const int t   = threadIdx.x;
    // XCD swizzle: 2048 % 8 == 0 -> bijective
    const int blk = (blockIdx.x & 7) * 256 + (blockIdx.x >> 3);
    const int b    = blk >> 9;          // image
    const int tile = blk & 511;
    const int ty   = tile >> 5;         // 0..15, 8 rows each
    const int tx   = tile & 31;         // 0..31, 4 cols each

    const int cg8 = t & 7;              // channel slot (8 ch)
    const int px  = t >> 3;             // 0..31 pixel id
    const int lx  = px & 3;             // 0..3
    const int ly  = px >> 2;            // 0..7

    const int gy = ty*8 + ly, gx = tx*4 + lx;
    const size_t img = (size_t)b * IMG;
    const size_t off = img + ((size_t)gy*WW + gx)*CC + cg8*8;

    const int y0 = ty*8 - 2, x0 = tx*4 - 2;

    // ---- q loads first (latency hides under staging) ----
    float4 qv0 = *(const float4*)(main_+off);
    float4 qv1 = *(const float4*)(main_+off+4);

    // ---- stage K+V halo as bf16: 1536 uint4 rows-of-8ch, 6 per thread ----
    float4 A[6], C[6];
    #pragma unroll
    for (int it = 0; it < 6; ++it) {
        const int u    = t + (it<<8);
        const int slot = u & 7;
        const int mat  = (u>>3) & 1;
        const int pos  = u >> 4;        // 0..95
        const int hy = pos >> 3, hx = pos & 7;
        const int yy = y0 + hy, xx = x0 + hx;
        A[it] = make_float4(0.f,0.f,0.f,0.f);
        C[it] = make_float4(0.f,0.f,0.f,0.f);
        if ((unsigned)yy < HH && (unsigned)xx < WW) {
            const float* g = (mat ? ref_value : ref) + img + ((size_t)yy*WW + xx)*CC + slot*8;
            A[it] = ((const float4*)g)[0];
            C[it] = ((const float4*)g)[1];
        }
    }
    #pragma unroll
    for (int it = 0; it < 6; ++it) {
        const int u    = t + (it<<8);
        const int slot = u & 7;
        const int mat  = (u>>3) & 1;
        const int pos  = u >> 4;
        kv4[pos*16 + mat*8 + slot] =
            make_uint4(pack2bf(A[it].x,A[it].y), pack2bf(A[it].z,A[it].w),
                       pack2bf(C[it].x,C[it].y), pack2bf(C[it].z,C[it].w));
    }

    __syncthreads();    // the ONLY barrier

    // ---- self-value loads: land while compute runs ----
    float4 mv0 = *(const float4*)(main_value+off);
    float4 mv1 = *(const float4*)(main_value+off+4);

    float q[8] = {qv0.x,qv0.y,qv0.z,qv0.w,qv1.x,qv1.y,qv1.z,qv1.w};

    // per-pixel softmax shift = self logit |q|^2 (exact, overflow-safe)
    float lq;
    {
        float a = 0.f;
        #pragma unroll
        for (int c = 0; c < 8; ++c) a = fmaf(q[c],q[c],a);
        lq = reduce8(a);
    }

    float o[8];
    #pragma unroll
    for (int c = 0; c < 8; ++c) o[c] = 0.f;
    float s = 0.f;

    // ---- 25 window positions ----
    #pragma unroll
    for (int di = 0; di < 5; ++di) {
        #pragma unroll
        for (int dj = 0; dj < 5; ++dj) {
            const int pos = (ly+di)*8 + (lx+dj);
            const uint4 kk = kv4[pos*16 + cg8];
            const uint4 vv = kv4[pos*16 + 8 + cg8];
            float k8[8], v8[8];
            unpack8(kk, k8);
            unpack8(vv, v8);
            float l = 0.f;
            #pragma unroll
            for (int c = 0; c < 8; ++c) l = fmaf(q[c], k8[c], l);
            l = reduce8(l);
            const float w = __expf(l - lq);     // arg bounded, no overflow
            s += w;
            #pragma unroll
            for (int c = 0; c < 8; ++c) o[c] = fmaf(w, v8[c], o[c]);
        }
    }

    // ---- self slot: weight exactly 1 ----
    {
        float mv[8] = {mv0.x,mv0.y,mv0.z,mv0.w,mv1.x,mv1.y,mv1.z,mv1.w};
        s += 1.f;
        #pragma unroll
        for (int c = 0; c < 8; ++c) o[c] += mv[c];
    }

    const float rs = 1.f/s;
    float4 r;
    r.x=o[0]*rs; r.y=o[1]*rs; r.z=o[2]*rs; r.w=o[3]*rs;
    *(float4*)(out+off) = r;
    r.x=o[4]*rs; r.y=o[5]*rs; r.z=o[6]*rs; r.w=o[7]*rs;
    *(float4*)(out+off+4) = r;
}

extern "C" void kernel_launch(void* const* d_in, const int* in_sizes, int n_in,
                              void* d_out, int out_size, void* d_ws, size_t ws_size,
                              hipStream_t stream) {
    const float* main_      = (const float*)d_in[0];
    const float* main_value = (const float*)d_in[1];
    const float* ref        = (const float*)d_in[2];
    const float* ref_value  = (const float*)d_in[3];
    float* out = (float*)d_out;

    // 4 images x 16 y-tiles x 32 x-tiles = 2048 blocks
    local_attn_kernel<<<dim3(2048), dim3(256), 0, stream>>>(
        main_, main_value, ref, ref_value, out);
}

// Round 10
// 131.903 us; speedup vs baseline: 1.3782x; 1.3782x over previous
//
#include <hip/hip_runtime.h>

#define HH 128
#define WW 128
#define CC 64
#define IMG (HH*WW*CC)

// tile: 8 rows x 4 cols = 32 px/block, 1 px per thread (8 lanes x 8 ch)
// halo: 12 rows x 8 cols = 96 positions
// LDS:  [pos(96)][mat(2)][slot(8)] uint4 (8 bf16 ch each) = 24576 B -> 6 blk/CU

__device__ __forceinline__ unsigned pack2bf(float a, float b){
  unsigned ua = __float_as_uint(a), ub = __float_as_uint(b);
  ua = (ua + 0x7fffu + ((ua>>16)&1u)) >> 16;            // RTN
  ub = (ub + 0x7fffu + ((ub>>16)&1u)) >> 16;
  return ua | (ub<<16);
}

__device__ __forceinline__ void unpack8(uint4 u, float* f){
  f[0]=__uint_as_float(u.x<<16); f[1]=__uint_as_float(u.x&0xffff0000u);
  f[2]=__uint_as_float(u.y<<16); f[3]=__uint_as_float(u.y&0xffff0000u);
  f[4]=__uint_as_float(u.z<<16); f[5]=__uint_as_float(u.z&0xffff0000u);
  f[6]=__uint_as_float(u.w<<16); f[7]=__uint_as_float(u.w&0xffff0000u);
}

template<int CTRL>
__device__ __forceinline__ float dpp_addstep(float x){
  int p = __builtin_amdgcn_update_dpp(0, __float_as_int(x), CTRL, 0xf, 0xf, true);
  return x + __int_as_float(p);
}
// sum across 8 consecutive lanes (groups aligned to lane&~7) — pure VALU/DPP
__device__ __forceinline__ float reduce8(float x){
  x = dpp_addstep<0xB1>(x);    // xor 1
  x = dpp_addstep<0x4E>(x);    // xor 2
  x = dpp_addstep<0x141>(x);   // row_half_mirror
  return x;
}

__global__ __launch_bounds__(256, 4) void local_attn_kernel(
    const float* __restrict__ main_,
    const float* __restrict__ main_value,
    const float* __restrict__ ref,
    const float* __restrict__ ref_value,
    float* __restrict__ out)
{
    __shared__ uint4 kv4[96*2*8];   // 24576 B

    const int t   = threadIdx.x;
    // XCD swizzle: 2048 % 8 == 0 -> bijective
    const int blk = (blockIdx.x & 7) * 256 + (blockIdx.x >> 3);
    const int b    = blk >> 9;          // image
    const int tile = blk & 511;
    const int ty   = tile >> 5;         // 0..15, 8 rows each
    const int tx   = tile & 31;         // 0..31, 4 cols each

    const int cg8 = t & 7;              // channel slot (8 ch)
    const int px  = t >> 3;             // 0..31 pixel id
    const int lx  = px & 3;             // 0..3
    const int ly  = px >> 2;            // 0..7

    const int gy = ty*8 + ly, gx = tx*4 + lx;
    const size_t img = (size_t)b * IMG;
    const size_t off = img + ((size_t)gy*WW + gx)*CC + cg8*8;

    const int y0 = ty*8 - 2, x0 = tx*4 - 2;

    // ---- streamed staging: load -> pack -> write, minimal liveness ----
    #pragma unroll
    for (int it = 0; it < 6; ++it) {
        const int u    = t + (it<<8);
        const int slot = u & 7;
        const int mat  = (u>>3) & 1;
        const int pos  = u >> 4;        // 0..95
        const int hy = pos >> 3, hx = pos & 7;
        const int yy = y0 + hy, xx = x0 + hx;
        float4 A = make_float4(0.f,0.f,0.f,0.f);
        float4 C = make_float4(0.f,0.f,0.f,0.f);
        if ((unsigned)yy < HH && (unsigned)xx < WW) {
            const float* g = (mat ? ref_value : ref) + img + ((size_t)yy*WW + xx)*CC + slot*8;
            A = ((const float4*)g)[0];
            C = ((const float4*)g)[1];
        }
        kv4[pos*16 + mat*8 + (slot ^ (pos & 7))] =
            make_uint4(pack2bf(A.x,A.y), pack2bf(A.z,A.w),
                       pack2bf(C.x,C.y), pack2bf(C.z,C.w));
    }

    __syncthreads();    // the ONLY barrier

    // ---- q load after barrier (keeps it out of staging liveness) ----
    float4 qv0 = *(const float4*)(main_+off);
    float4 qv1 = *(const float4*)(main_+off+4);
    float q[8] = {qv0.x,qv0.y,qv0.z,qv0.w,qv1.x,qv1.y,qv1.z,qv1.w};

    // per-pixel softmax shift = self logit |q|^2 (exact, overflow-safe)
    float lq;
    {
        float a = 0.f;
        #pragma unroll
        for (int c = 0; c < 8; ++c) a = fmaf(q[c],q[c],a);
        lq = reduce8(a);
    }

    float o[8];
    #pragma unroll
    for (int c = 0; c < 8; ++c) o[c] = 0.f;
    float s = 0.f;

    // ---- 25 window positions ----
    #pragma unroll
    for (int di = 0; di < 5; ++di) {
        #pragma unroll
        for (int dj = 0; dj < 5; ++dj) {
            const int pos = (ly+di)*8 + (lx+dj);
            const int sw  = cg8 ^ (pos & 7);
            const uint4 kk = kv4[pos*16 + sw];
            const uint4 vv = kv4[pos*16 + 8 + sw];
            float k8[8], v8[8];
            unpack8(kk, k8);
            unpack8(vv, v8);
            float l = 0.f;
            #pragma unroll
            for (int c = 0; c < 8; ++c) l = fmaf(q[c], k8[c], l);
            l = reduce8(l);
            const float w = __expf(l - lq);     // arg bounded, no overflow
            s += w;
            #pragma unroll
            for (int c = 0; c < 8; ++c) o[c] = fmaf(w, v8[c], o[c]);
        }
    }

    // ---- self slot (weight exactly 1), value loaded only now ----
    {
        float4 mv0 = *(const float4*)(main_value+off);
        float4 mv1 = *(const float4*)(main_value+off+4);
        s += 1.f;
        o[0] += mv0.x; o[1] += mv0.y; o[2] += mv0.z; o[3] += mv0.w;
        o[4] += mv1.x; o[5] += mv1.y; o[6] += mv1.z; o[7] += mv1.w;
    }

    const float rs = 1.f/s;
    float4 r;
    r.x=o[0]*rs; r.y=o[1]*rs; r.z=o[2]*rs; r.w=o[3]*rs;
    *(float4*)(out+off) = r;
    r.x=o[4]*rs; r.y=o[5]*rs; r.z=o[6]*rs; r.w=o[7]*rs;
    *(float4*)(out+off+4) = r;
}

extern "C" void kernel_launch(void* const* d_in, const int* in_sizes, int n_in,
                              void* d_out, int out_size, void* d_ws, size_t ws_size,
                              hipStream_t stream) {
    const float* main_      = (const float*)d_in[0];
    const float* main_value = (const float*)d_in[1];
    const float* ref        = (const float*)d_in[2];
    const float* ref_value  = (const float*)d_in[3];
    float* out = (float*)d_out;

    // 4 images x 16 y-tiles x 32 x-tiles = 2048 blocks
    local_attn_kernel<<<dim3(2048), dim3(256), 0, stream>>>(
        main_, main_value, ref, ref_value, out);
}